// Round 5
// baseline (341.063 us; speedup 1.0000x reference)
//
#include <hip/hip_runtime.h>
#include <hip/hip_bf16.h>

using bf16 = __hip_bfloat16;

constexpr int B_ = 32, S_ = 4096, V_ = 256, E_ = 128, H_ = 256, NM_ = 16;
constexpr int GH = 2 * H_;        // 512
constexpr int NC = 128, L_ = 32;  // chunked scan: 128 chunks of 32 steps

typedef __attribute__((ext_vector_type(8))) short bf16x8;
typedef __attribute__((ext_vector_type(4))) float f32x4;

__device__ __forceinline__ float b2f(unsigned short u) {
  union { float f; unsigned int i; } x; x.i = ((unsigned int)u) << 16; return x.f;
}
// RNE bf16 pack, no NaN path (all values finite here): 4 VALU ops
__device__ __forceinline__ unsigned short f2b(float f) {
  unsigned int i = __builtin_bit_cast(unsigned int, f);
  return (unsigned short)((i + 0x7fffu + ((i >> 16) & 1u)) >> 16);
}

// h_t = a*h_{t-1} + bt;  a = sigmoid(-gate), bt = sigmoid(gate)*g(hid)
// native exp2/rcp (~1ulp) instead of IEEE divide sequences
__device__ __forceinline__ void step_ab(float gate, float hid, float& a, float& bt) {
  const float LOG2E = 1.4426950408889634f;
  float e  = __builtin_amdgcn_exp2f(gate * LOG2E);                         // exp(gate)
  a = __builtin_amdgcn_rcpf(1.0f + e);                                     // sigmoid(-gate)
  float sn = __builtin_amdgcn_rcpf(1.0f + __builtin_amdgcn_exp2f(-hid * LOG2E));
  float g  = (hid >= 0.0f) ? (hid + 0.5f) : sn;
  bt = (1.0f - a) * g;
}

// A-tile swizzle (16KB, [32 rows][512 bytes]) and LDS-gh swizzle ([32][256] u32)
#define ATS(row, bcol) (((row) << 9) | ((bcol) ^ (((row) & 7) << 4)))
#define GHS(row, col)  (((row) << 8) | ((col) ^ ((((row) >> 2) & 3) << 4)))

// ---------------------------------------------------------------- tables
// T0[v][0:256]=a, [256:512]=bt, [512:768]=align   (f32)
// Wpk = Wl packed into MFMA B-fragment order, bf16:
//   fid = layer*16384 + kk*2048 + grp*64 + lane
//   holds Wl[layer][grp*16 + (lane&15)][kk*32 + (lane>>4)*8 + e], e=0..7
__global__ __launch_bounds__(256) void build_tables(
    const float* __restrict__ emb, const float* __restrict__ W0,
    const float* __restrict__ b0, const float* __restrict__ Walign,
    const float* __restrict__ Wl, float* __restrict__ T0, bf16* __restrict__ Wpk) {
  const int v = blockIdx.x;
  const int t = threadIdx.x;
  __shared__ float e[E_];
  if (t < E_) e[t] = emb[v * E_ + t];
  __syncthreads();
  const float4* w0g = (const float4*)(W0 + (size_t)t * E_);
  const float4* w0h = (const float4*)(W0 + (size_t)(t + 256) * E_);
  const float4* wal = (const float4*)(Walign + (size_t)t * E_);
  float g = b0[t], hd = b0[t + 256], al = 0.0f;
  #pragma unroll 8
  for (int k = 0; k < E_ / 4; ++k) {
    float4 ev = *(const float4*)(e + 4 * k);
    float4 ga = w0g[k]; g  += ga.x * ev.x + ga.y * ev.y + ga.z * ev.z + ga.w * ev.w;
    float4 hb = w0h[k]; hd += hb.x * ev.x + hb.y * ev.y + hb.z * ev.z + hb.w * ev.w;
    float4 aw = wal[k]; al += aw.x * ev.x + aw.y * ev.y + aw.z * ev.z + aw.w * ev.w;
  }
  float a, btv; step_ab(g, hd, a, btv);
  T0[(size_t)v * 768 + t]       = a;
  T0[(size_t)v * 768 + 256 + t] = btv;
  T0[(size_t)v * 768 + 512 + t] = al;

  const int fid = v * 256 + t;          // 65536 threads cover 32768 fragments
  if (fid < 32768) {
    const int layer = fid >> 14;
    const int kk   = (fid >> 11) & 7;
    const int grp  = (fid >> 6) & 31;
    const int lane = fid & 63;
    const int row = grp * 16 + (lane & 15);
    const int k0  = kk * 32 + (lane >> 4) * 8;
    const float* src = Wl + (((size_t)layer * 512 + row) * 256 + k0);
    bf16* dst = Wpk + (size_t)fid * 8;
    #pragma unroll
    for (int e2 = 0; e2 < 8; ++e2) dst[e2] = __float2bfloat16(src[e2]);
  }
}

// ---------------------------------------------------------------- layer-0 scan A
__global__ __launch_bounds__(256) void scanA_l0(const int* __restrict__ x, const float* __restrict__ T0,
                                                float* __restrict__ cAB) {
  const int b = blockIdx.y;
  const int wv = threadIdx.x >> 6, lane = threadIdx.x & 63;
  const int c = blockIdx.x * 4 + wv;
  const int t4 = lane * 4;
  const int* xp = x + (size_t)b * S_ + (size_t)c * L_;
  float A0=1,A1=1,A2=1,A3=1, B0=0,B1=0,B2=0,B3=0;
  #pragma unroll 4
  for (int t = 0; t < L_; ++t) {
    const float* tp = T0 + (size_t)xp[t] * 768;
    float4 a4 = *(const float4*)(tp + t4);
    float4 b4 = *(const float4*)(tp + 256 + t4);
    A0 = a4.x*A0; B0 = a4.x*B0 + b4.x;
    A1 = a4.y*A1; B1 = a4.y*B1 + b4.y;
    A2 = a4.z*A2; B2 = a4.z*B2 + b4.z;
    A3 = a4.w*A3; B3 = a4.w*B3 + b4.w;
  }
  float* o = cAB + (size_t)(b * NC + c) * 2 * H_;
  *(float4*)(o + t4)      = make_float4(A0, A1, A2, A3);
  *(float4*)(o + H_ + t4) = make_float4(B0, B1, B2, B3);
}

// ---------------------------------------------------------------- layer-0 scan C (self-prefix) + align residual
__global__ __launch_bounds__(256) void scanC_l0(const int* __restrict__ x, const float* __restrict__ T0,
                                                const float* __restrict__ cAB, bf16* __restrict__ h) {
  const int b = blockIdx.y;
  const int wv = threadIdx.x >> 6, lane = threadIdx.x & 63;
  const int c = blockIdx.x * 4 + wv;
  const int t4 = lane * 4;
  float4 hr = make_float4(0.5f, 0.5f, 0.5f, 0.5f);
  {
    const float* pk0 = cAB + (size_t)b * NC * 2 * H_ + t4;
    #pragma unroll 4
    for (int k = 0; k < c; ++k) {
      float4 a4 = *(const float4*)(pk0);
      float4 b4 = *(const float4*)(pk0 + H_);
      hr.x = a4.x*hr.x + b4.x; hr.y = a4.y*hr.y + b4.y;
      hr.z = a4.z*hr.z + b4.z; hr.w = a4.w*hr.w + b4.w;
      pk0 += 2 * H_;
    }
  }
  const int* xp = x + (size_t)b * S_ + (size_t)c * L_;
  unsigned short* hp = (unsigned short*)(h + ((size_t)b * S_ + (size_t)c * L_) * H_);
  #pragma unroll 4
  for (int t = 0; t < L_; ++t) {
    const float* tp = T0 + (size_t)xp[t] * 768;
    float4 a4 = *(const float4*)(tp + t4);
    float4 b4 = *(const float4*)(tp + 256 + t4);
    float4 r4 = *(const float4*)(tp + 512 + t4);
    hr.x = a4.x*hr.x + b4.x;
    hr.y = a4.y*hr.y + b4.y;
    hr.z = a4.z*hr.z + b4.z;
    hr.w = a4.w*hr.w + b4.w;
    ushort4 o;
    o.x = f2b(hr.x + r4.x);
    o.y = f2b(hr.y + r4.y);
    o.z = f2b(hr.z + r4.z);
    o.w = f2b(hr.w + r4.w);
    *(ushort4*)(hp + t4) = o;
    hp += H_;
  }
}

// ---------------------------------------------------------------- fused-layer building blocks
__device__ __forceinline__ void gemm_tile(const char* smem, const bf16* __restrict__ Wp,
                                          int lane, int wave,
                                          f32x4 (&accG)[2][4], f32x4 (&accH)[2][4]) {
  const int l15 = lane & 15, lhi = lane >> 4;
  #pragma unroll
  for (int kk = 0; kk < 8; ++kk) {
    const int kb = kk * 64 + lhi * 16;
    bf16x8 af[2], bG[4], bH[4];
    #pragma unroll
    for (int ni = 0; ni < 4; ++ni) {
      bG[ni] = *(const bf16x8*)(Wp + ((size_t)(kk * 2048 + (wave * 4 + ni) * 64 + lane)) * 8);
      bH[ni] = *(const bf16x8*)(Wp + ((size_t)(kk * 2048 + (16 + wave * 4 + ni) * 64 + lane)) * 8);
    }
    #pragma unroll
    for (int mi = 0; mi < 2; ++mi) {
      const int r = mi * 16 + l15;
      af[mi] = *(const bf16x8*)(smem + ATS(r, kb));
    }
    #pragma unroll
    for (int mi = 0; mi < 2; ++mi)
      #pragma unroll
      for (int ni = 0; ni < 4; ++ni) {
        accG[mi][ni] = __builtin_amdgcn_mfma_f32_16x16x32_bf16(af[mi], bG[ni], accG[mi][ni], 0, 0, 0);
        accH[mi][ni] = __builtin_amdgcn_mfma_f32_16x16x32_bf16(af[mi], bH[ni], accH[mi][ni], 0, 0, 0);
      }
  }
}

__device__ __forceinline__ void transform_to_lds(unsigned int* ghl,
                                                 const f32x4 (&accG)[2][4], const f32x4 (&accH)[2][4],
                                                 const float* __restrict__ bias, int lane, int wave) {
  const int l15 = lane & 15, lhi = lane >> 4;
  #pragma unroll
  for (int ni = 0; ni < 4; ++ni) {
    const int colG = wave * 64 + ni * 16 + l15;
    const float bg = bias[colG], bh = bias[colG + 256];
    #pragma unroll
    for (int mi = 0; mi < 2; ++mi)
      #pragma unroll
      for (int j = 0; j < 4; ++j) {
        const int row = mi * 16 + lhi * 4 + j;
        float a, btv;
        step_ab(accG[mi][ni][j] + bg, accH[mi][ni][j] + bh, a, btv);
        ghl[GHS(row, colG)] = ((unsigned int)f2b(a) << 16) | f2b(btv);
      }
  }
}

// ---------------------------------------------------------------- fused mid layer
// phase1: h-tile -> GEMM1 -> (a,bt) in LDS -> per-channel compose -> cABout
// phase2: + prefix(cABin) -> replay+residual -> h1 overwrites A-tile -> GEMM2
//         -> (a2,b2) in LDS -> compose -> cABout; tail chunks spill gh/h1
__global__ __launch_bounds__(256, 3) void fused_layer(
    const bf16* __restrict__ hin,
    const bf16* __restrict__ Wp1, const float* __restrict__ bias1,
    const bf16* __restrict__ Wp2, const float* __restrict__ bias2,
    const float* __restrict__ cABin, float* __restrict__ cABout,
    unsigned int* __restrict__ ghT, bf16* __restrict__ hio, int phase2) {
  __shared__ __align__(16) char smem[49152];   // A-tile 16KB | gh 32KB
  unsigned int* ghl = (unsigned int*)(smem + 16384);
  const int bid = blockIdx.x;
  const int c = bid & (NC - 1), b = bid >> 7;
  const size_t row0 = (size_t)b * S_ + (size_t)c * L_;
  const int tid = threadIdx.x, lane = tid & 63, wave = tid >> 6;

  const char* Ag = (const char*)(hin + row0 * 256);
  #pragma unroll
  for (int it = 0; it < 4; ++it) {
    const int o = it * 4096 + tid * 16;
    const int row = o >> 9, bb = o & 511;
    const int src = (row << 9) | (bb ^ ((row & 7) << 4));   // inverse-swizzled source
    char* lbase = smem + it * 4096 + wave * 1024;           // wave-uniform base
    __builtin_amdgcn_global_load_lds((const __attribute__((address_space(1))) void*)(Ag + src),
                                     (__attribute__((address_space(3))) void*)lbase, 16, 0, 0);
  }
  __syncthreads();

  {
    f32x4 accG[2][4] = {}, accH[2][4] = {};
    gemm_tile(smem, Wp1, lane, wave, accG, accH);
    transform_to_lds(ghl, accG, accH, bias1, lane, wave);
  }
  __syncthreads();

  const int ch = tid;
  if (!phase2) {
    float A = 1.0f, Bv = 0.0f;
    #pragma unroll 8
    for (int t = 0; t < L_; ++t) {
      unsigned int u = ghl[GHS(t, ch)];
      float a = b2f(u >> 16), bb = b2f(u & 0xffffu);
      A = a * A; Bv = a * Bv + bb;
    }
    float* o = cABout + ((size_t)b * NC + c) * 2 * H_;
    o[ch] = A; o[H_ + ch] = Bv;
    return;
  }

  // ---- phase 2 ----
  float hp = 0.5f;
  {
    const float* pc = cABin + (size_t)b * NC * 2 * H_ + ch;
    #pragma unroll 4
    for (int k = 0; k < c; ++k) { hp = pc[0] * hp + pc[H_]; pc += 2 * H_; }
  }
  unsigned int hpk[16];
  #pragma unroll
  for (int t = 0; t < L_; ++t) {
    unsigned int u = ghl[GHS(t, ch)];
    hp = b2f(u >> 16) * hp + b2f(u & 0xffffu);
    float h1 = hp + b2f(*(const unsigned short*)(smem + ATS(t, ch * 2)));
    unsigned short hb = f2b(h1);
    if ((t & 1) == 0) hpk[t >> 1] = hb;
    else              hpk[t >> 1] |= ((unsigned int)hb << 16);
  }
  __syncthreads();                      // all gh reads + h0 residual reads done
  #pragma unroll
  for (int t = 0; t < L_; ++t) {
    unsigned short hb = (unsigned short)((t & 1) ? (hpk[t >> 1] >> 16) : (hpk[t >> 1] & 0xffffu));
    *(unsigned short*)(smem + ATS(t, ch * 2)) = hb;     // A-tile := h1
  }
  __syncthreads();

  {
    f32x4 accG[2][4] = {}, accH[2][4] = {};
    gemm_tile(smem, Wp2, lane, wave, accG, accH);
    transform_to_lds(ghl, accG, accH, bias2, lane, wave);
  }
  __syncthreads();

  {
    float A = 1.0f, Bv = 0.0f;
    #pragma unroll 8
    for (int t = 0; t < L_; ++t) {
      unsigned int u = ghl[GHS(t, ch)];
      float a = b2f(u >> 16), bb = b2f(u & 0xffffu);
      A = a * A; Bv = a * Bv + bb;
    }
    float* o = cABout + ((size_t)b * NC + c) * 2 * H_;
    o[ch] = A; o[H_ + ch] = Bv;
  }

  if (c >= NC - 4) {
    // spill (a2,b2) strip + h1 tile for the tail scan
    const size_t tb = ((size_t)(b * 4 + (c - (NC - 4))) * 32) * 256;
    #pragma unroll
    for (int i = 0; i < 32; ++i) {
      const int idx = tid + i * 256;
      const int row = idx >> 8, col = idx & 255;
      ghT[tb + idx] = ghl[GHS(row, col)];
    }
    #pragma unroll
    for (int i = 0; i < 4; ++i) {
      const int idx = tid + i * 256;
      const int row = idx >> 5, colb = (idx & 31) * 16;
      bf16x8 v = *(const bf16x8*)(smem + ATS(row, colb));
      *(bf16x8*)(hio + (row0 + row) * 256 + colb / 2) = v;
    }
  }
}

// ---------------------------------------------------------------- tail scan (last 4 chunks, layer 2)
__global__ __launch_bounds__(256) void scanC_tail(const unsigned int* __restrict__ ghT,
                                                  const float* __restrict__ cAB,
                                                  bf16* __restrict__ h) {
  const int b = blockIdx.x;
  const int wv = threadIdx.x >> 6, lane = threadIdx.x & 63;
  const int c = (NC - 4) + wv;
  const int t4 = lane * 4;
  float4 hr = make_float4(0.5f, 0.5f, 0.5f, 0.5f);
  {
    const float* pk0 = cAB + (size_t)b * NC * 2 * H_ + t4;
    #pragma unroll 4
    for (int k = 0; k < c; ++k) {
      float4 a4 = *(const float4*)(pk0);
      float4 b4 = *(const float4*)(pk0 + H_);
      hr.x = a4.x*hr.x + b4.x; hr.y = a4.y*hr.y + b4.y;
      hr.z = a4.z*hr.z + b4.z; hr.w = a4.w*hr.w + b4.w;
      pk0 += 2 * H_;
    }
  }
  const unsigned int* p = ghT + ((size_t)(b * 4 + wv) * 32) * 256 + t4;
  unsigned short* hp = (unsigned short*)(h + ((size_t)b * S_ + (size_t)c * L_) * H_);
  #pragma unroll 4
  for (int t = 0; t < L_; ++t) {
    uint4 pk = *(const uint4*)(p);
    ushort4 ru = *(const ushort4*)(hp + t4);
    hr.x = b2f(pk.x >> 16)*hr.x + b2f(pk.x & 0xffff);
    hr.y = b2f(pk.y >> 16)*hr.y + b2f(pk.y & 0xffff);
    hr.z = b2f(pk.z >> 16)*hr.z + b2f(pk.z & 0xffff);
    hr.w = b2f(pk.w >> 16)*hr.w + b2f(pk.w & 0xffff);
    ushort4 ov;
    ov.x = f2b(hr.x + b2f(ru.x));
    ov.y = f2b(hr.y + b2f(ru.y));
    ov.z = f2b(hr.z + b2f(ru.z));
    ov.w = f2b(hr.w + b2f(ru.w));
    *(ushort4*)(hp + t4) = ov;
    p += 256; hp += H_;
  }
}

// ---------------------------------------------------------------- output logits (last NM positions)
__global__ __launch_bounds__(256) void out_logits(const bf16* __restrict__ h,
                                                  const float* __restrict__ Wout,
                                                  const float* __restrict__ bout,
                                                  float* __restrict__ out) {
  const int r = blockIdx.x;            // b*NM + si
  const int b = r >> 4, si = r & 15;
  const int v = threadIdx.x;
  __shared__ float hs[H_];
  const size_t t = (size_t)b * S_ + (S_ - NM_ + si);
  hs[v] = b2f(((const unsigned short*)h)[t * H_ + v]);
  __syncthreads();
  float acc = bout[v];
  const float4* w4 = (const float4*)(Wout + (size_t)v * H_);
  #pragma unroll 8
  for (int k = 0; k < H_ / 4; ++k) {
    float4 wv = w4[k];
    float4 hv = *(const float4*)(hs + 4 * k);
    acc += wv.x * hv.x + wv.y * hv.y + wv.z * hv.z + wv.w * hv.w;
  }
  out[(size_t)r * V_ + v] = acc;
}

// ----------------------------------------------------------------
extern "C" void kernel_launch(void* const* d_in, const int* in_sizes, int n_in,
                              void* d_out, int out_size, void* d_ws, size_t ws_size,
                              hipStream_t stream) {
  const int*   x      = (const int*)d_in[0];
  const float* emb    = (const float*)d_in[1];
  const float* W0     = (const float*)d_in[2];
  const float* b0     = (const float*)d_in[3];
  const float* Wl     = (const float*)d_in[4];
  const float* bl     = (const float*)d_in[5];
  const float* Walign = (const float*)d_in[6];
  const float* Wout   = (const float*)d_in[7];
  const float* bout   = (const float*)d_in[8];
  (void)in_sizes; (void)n_in; (void)out_size; (void)ws_size;

  char* ws = (char*)d_ws;
  size_t off = 0;
  bf16*  h    = (bf16*)(ws + off);  off += (size_t)B_ * S_ * H_ * 2;       // 67 MB
  float* cAB0 = (float*)(ws + off); off += (size_t)B_ * NC * 2 * H_ * 4;   // 8.4 MB
  float* cAB1 = (float*)(ws + off); off += (size_t)B_ * NC * 2 * H_ * 4;   // 8.4 MB
  float* cAB2 = (float*)(ws + off); off += (size_t)B_ * NC * 2 * H_ * 4;   // 8.4 MB
  unsigned int* ghT = (unsigned int*)(ws + off); off += (size_t)B_ * 4 * 32 * 256 * 4; // 4 MB
  float* T0   = (float*)(ws + off); off += (size_t)V_ * 768 * 4;           // 768 KB
  bf16*  Wpk  = (bf16*)(ws + off);  off += (size_t)2 * GH * H_ * 2;        // 512 KB

  build_tables<<<256, 256, 0, stream>>>(emb, W0, b0, Walign, Wl, T0, Wpk);

  dim3 gscan(NC / 4, B_);
  // layer 0
  scanA_l0<<<gscan, 256, 0, stream>>>(x, T0, cAB0);
  scanC_l0<<<gscan, 256, 0, stream>>>(x, T0, cAB0, h);

  const bf16* Wpk2 = Wpk + (size_t)GH * H_;
  // phase 1: layer-1 chunk summaries only
  fused_layer<<<B_ * NC, 256, 0, stream>>>(h, Wpk, bl, Wpk2, bl + GH,
                                           cAB1, cAB1, ghT, h, 0);
  // phase 2: recompute layer-1 gh, replay to h1, GEMM2, layer-2 summaries + tails
  fused_layer<<<B_ * NC, 256, 0, stream>>>(h, Wpk, bl, Wpk2, bl + GH,
                                           cAB1, cAB2, ghT, h, 1);

  scanC_tail<<<B_, 256, 0, stream>>>(ghT, cAB2, h);
  out_logits<<<B_ * NM_, 256, 0, stream>>>(h, Wout, bout, (float*)d_out);
}

// Round 6
// 287.219 us; speedup vs baseline: 1.1875x; 1.1875x over previous
//
#include <hip/hip_runtime.h>
#include <hip/hip_bf16.h>

using bf16 = __hip_bfloat16;

constexpr int B_ = 32, S_ = 4096, V_ = 256, E_ = 128, H_ = 256, NM_ = 16;
constexpr int GH = 2 * H_;        // 512
constexpr int NC = 128, L_ = 32;  // chunked scan: 128 chunks of 32 steps

typedef __attribute__((ext_vector_type(8))) short bf16x8;
typedef __attribute__((ext_vector_type(4))) float f32x4;

__device__ __forceinline__ float b2f(unsigned short u) {
  union { float f; unsigned int i; } x; x.i = ((unsigned int)u) << 16; return x.f;
}
// RNE bf16 pack, no NaN path (all values finite here): ~4 VALU ops
__device__ __forceinline__ unsigned short f2b(float f) {
  unsigned int i = __builtin_bit_cast(unsigned int, f);
  return (unsigned short)((i + 0x7fffu + ((i >> 16) & 1u)) >> 16);
}

// h_t = a*h_{t-1} + bt;  a = sigmoid(-gate), bt = sigmoid(gate)*g(hid)
// native v_exp_f32 / v_rcp_f32 (~1 ulp, invisible at bf16) instead of IEEE div
__device__ __forceinline__ void step_ab(float gate, float hid, float& a, float& bt) {
  const float LOG2E = 1.4426950408889634f;
  float e  = __builtin_amdgcn_exp2f(gate * LOG2E);                     // exp(gate)
  a = __builtin_amdgcn_rcpf(1.0f + e);                                 // sigmoid(-gate)
  float sn = __builtin_amdgcn_rcpf(1.0f + __builtin_amdgcn_exp2f(-hid * LOG2E));
  float g  = (hid >= 0.0f) ? (hid + 0.5f) : sn;
  bt = (1.0f - a) * g;
}

// ---------------------------------------------------------------- tables
// T0[v][0:256]=a, [256:512]=bt, [512:768]=align   (f32)
// Wpk = Wl packed into MFMA B-fragment order, bf16:
//   fid = layer*16384 + kk*2048 + grp*64 + lane
//   holds Wl[layer][grp*16 + (lane&15)][kk*32 + (lane>>4)*8 + e], e=0..7
__global__ __launch_bounds__(256) void build_tables(
    const float* __restrict__ emb, const float* __restrict__ W0,
    const float* __restrict__ b0, const float* __restrict__ Walign,
    const float* __restrict__ Wl, float* __restrict__ T0, bf16* __restrict__ Wpk) {
  const int v = blockIdx.x;
  const int t = threadIdx.x;
  __shared__ float e[E_];
  if (t < E_) e[t] = emb[v * E_ + t];
  __syncthreads();
  const float4* w0g = (const float4*)(W0 + (size_t)t * E_);
  const float4* w0h = (const float4*)(W0 + (size_t)(t + 256) * E_);
  const float4* wal = (const float4*)(Walign + (size_t)t * E_);
  float g = b0[t], hd = b0[t + 256], al = 0.0f;
  #pragma unroll 8
  for (int k = 0; k < E_ / 4; ++k) {
    float4 ev = *(const float4*)(e + 4 * k);
    float4 ga = w0g[k]; g  += ga.x * ev.x + ga.y * ev.y + ga.z * ev.z + ga.w * ev.w;
    float4 hb = w0h[k]; hd += hb.x * ev.x + hb.y * ev.y + hb.z * ev.z + hb.w * ev.w;
    float4 aw = wal[k]; al += aw.x * ev.x + aw.y * ev.y + aw.z * ev.z + aw.w * ev.w;
  }
  float a, btv; step_ab(g, hd, a, btv);
  T0[(size_t)v * 768 + t]       = a;
  T0[(size_t)v * 768 + 256 + t] = btv;
  T0[(size_t)v * 768 + 512 + t] = al;

  const int fid = v * 256 + t;          // 65536 threads cover 32768 fragments
  if (fid < 32768) {
    const int layer = fid >> 14;
    const int kk   = (fid >> 11) & 7;
    const int grp  = (fid >> 6) & 31;
    const int lane = fid & 63;
    const int row = grp * 16 + (lane & 15);
    const int k0  = kk * 32 + (lane >> 4) * 8;
    const float* src = Wl + (((size_t)layer * 512 + row) * 256 + k0);
    bf16* dst = Wpk + (size_t)fid * 8;
    #pragma unroll
    for (int e2 = 0; e2 < 8; ++e2) dst[e2] = __float2bfloat16(src[e2]);
  }
}

// ---------------------------------------------------------------- layer-0 scan A
__global__ __launch_bounds__(256) void scanA_l0(const int* __restrict__ x, const float* __restrict__ T0,
                                                float* __restrict__ cAB) {
  const int b = blockIdx.y;
  const int wv = threadIdx.x >> 6, lane = threadIdx.x & 63;
  const int c = blockIdx.x * 4 + wv;
  const int t4 = lane * 4;
  const int* xp = x + (size_t)b * S_ + (size_t)c * L_;
  float A0=1,A1=1,A2=1,A3=1, B0=0,B1=0,B2=0,B3=0;
  #pragma unroll 4
  for (int t = 0; t < L_; ++t) {
    const float* tp = T0 + (size_t)xp[t] * 768;
    float4 a4 = *(const float4*)(tp + t4);
    float4 b4 = *(const float4*)(tp + 256 + t4);
    A0 = a4.x*A0; B0 = a4.x*B0 + b4.x;
    A1 = a4.y*A1; B1 = a4.y*B1 + b4.y;
    A2 = a4.z*A2; B2 = a4.z*B2 + b4.z;
    A3 = a4.w*A3; B3 = a4.w*B3 + b4.w;
  }
  float* o = cAB + (size_t)(b * NC + c) * 2 * H_;
  *(float4*)(o + t4)      = make_float4(A0, A1, A2, A3);
  *(float4*)(o + H_ + t4) = make_float4(B0, B1, B2, B3);
}

// ---------------------------------------------------------------- layer-0 scan C (self-prefix) + align residual
__global__ __launch_bounds__(256) void scanC_l0(const int* __restrict__ x, const float* __restrict__ T0,
                                                const float* __restrict__ cAB, bf16* __restrict__ h) {
  const int b = blockIdx.y;
  const int wv = threadIdx.x >> 6, lane = threadIdx.x & 63;
  const int c = blockIdx.x * 4 + wv;
  const int t4 = lane * 4;
  float4 hr = make_float4(0.5f, 0.5f, 0.5f, 0.5f);
  {
    const float* pk0 = cAB + (size_t)b * NC * 2 * H_ + t4;
    #pragma unroll 4
    for (int k = 0; k < c; ++k) {
      float4 a4 = *(const float4*)(pk0);
      float4 b4 = *(const float4*)(pk0 + H_);
      hr.x = a4.x*hr.x + b4.x; hr.y = a4.y*hr.y + b4.y;
      hr.z = a4.z*hr.z + b4.z; hr.w = a4.w*hr.w + b4.w;
      pk0 += 2 * H_;
    }
  }
  const int* xp = x + (size_t)b * S_ + (size_t)c * L_;
  unsigned short* hp = (unsigned short*)(h + ((size_t)b * S_ + (size_t)c * L_) * H_);
  #pragma unroll 4
  for (int t = 0; t < L_; ++t) {
    const float* tp = T0 + (size_t)xp[t] * 768;
    float4 a4 = *(const float4*)(tp + t4);
    float4 b4 = *(const float4*)(tp + 256 + t4);
    float4 r4 = *(const float4*)(tp + 512 + t4);
    hr.x = a4.x*hr.x + b4.x;
    hr.y = a4.y*hr.y + b4.y;
    hr.z = a4.z*hr.z + b4.z;
    hr.w = a4.w*hr.w + b4.w;
    ushort4 o;
    o.x = f2b(hr.x + r4.x);
    o.y = f2b(hr.y + r4.y);
    o.z = f2b(hr.z + r4.z);
    o.w = f2b(hr.w + r4.w);
    *(ushort4*)(hp + t4) = o;
    hp += H_;
  }
}

// ---------------------------------------------------------------- fused GEMM + scanA (mid layers)
// block = one chunk (32 t x 512 cols). Wave w owns gate cols [w*64,w*64+64) and
// hid cols +256 -> (gate,hid) pairs land in the same lane's accs. In-register
// transform -> packed u32 (a|bt) gh stores; shuffle-compose -> cAB. LDS = 16KB.
__global__ __launch_bounds__(256, 4) void gemm_scanA(
    const bf16* __restrict__ Ain, const bf16* __restrict__ Wp,
    const float* __restrict__ bias, unsigned int* __restrict__ gh2,
    float* __restrict__ cAB, int cSkip) {
  __shared__ __align__(16) char smem[16384];   // A tile only
  const int bid = blockIdx.x;
  const int c = bid & (NC - 1), b = bid >> 7;
  const size_t row0 = (size_t)b * S_ + (size_t)c * L_;
  const int tid = threadIdx.x, lane = tid & 63, wave = tid >> 6;

  const char* Ag = (const char*)(Ain + row0 * 256);
  #pragma unroll
  for (int it = 0; it < 4; ++it) {
    const int o = it * 4096 + tid * 16;        // linear LDS dest offset
    const int row = o >> 9, bb = o & 511;
    const int src = (row << 9) | (bb ^ ((row & 7) << 4));   // inverse-swizzled source
    char* lbase = smem + it * 4096 + wave * 1024;           // wave-uniform base
    __builtin_amdgcn_global_load_lds((const __attribute__((address_space(1))) void*)(Ag + src),
                                     (__attribute__((address_space(3))) void*)lbase, 16, 0, 0);
  }
  __syncthreads();

  const int l15 = lane & 15, lhi = lane >> 4;
  f32x4 accG[2][4] = {}, accH[2][4] = {};
  #pragma unroll
  for (int kk = 0; kk < 8; ++kk) {
    const int kb = kk * 64 + lhi * 16;
    bf16x8 af[2], bG[4], bH[4];
    #pragma unroll
    for (int ni = 0; ni < 4; ++ni) {
      bG[ni] = *(const bf16x8*)(Wp + ((size_t)(kk * 2048 + (wave * 4 + ni) * 64 + lane)) * 8);
      bH[ni] = *(const bf16x8*)(Wp + ((size_t)(kk * 2048 + (16 + wave * 4 + ni) * 64 + lane)) * 8);
    }
    #pragma unroll
    for (int mi = 0; mi < 2; ++mi) {
      const int r = mi * 16 + l15;
      af[mi] = *(const bf16x8*)(smem + ((r << 9) | (kb ^ ((r & 7) << 4))));
    }
    #pragma unroll
    for (int mi = 0; mi < 2; ++mi)
      #pragma unroll
      for (int ni = 0; ni < 4; ++ni) {
        accG[mi][ni] = __builtin_amdgcn_mfma_f32_16x16x32_bf16(af[mi], bG[ni], accG[mi][ni], 0, 0, 0);
        accH[mi][ni] = __builtin_amdgcn_mfma_f32_16x16x32_bf16(af[mi], bH[ni], accH[mi][ni], 0, 0, 0);
      }
  }

  // in-register transform + packed stores + chunk composition
  const bool doStore = (c >= cSkip);
  float* o = cAB + ((size_t)b * NC + c) * 2 * H_;
  #pragma unroll
  for (int ni = 0; ni < 4; ++ni) {
    const int colG = wave * 64 + ni * 16 + l15;
    const float bg = bias[colG], bh = bias[colG + 256];
    float segA[2], segB[2];
    #pragma unroll
    for (int mi = 0; mi < 2; ++mi) {
      float Aa = 1.0f, Bb = 0.0f;
      #pragma unroll
      for (int j = 0; j < 4; ++j) {
        float a, btv;
        step_ab(accG[mi][ni][j] + bg, accH[mi][ni][j] + bh, a, btv);
        const unsigned short ua = f2b(a), ub = f2b(btv);
        if (doStore) {
          const int lr = mi * 16 + lhi * 4 + j;
          gh2[(row0 + lr) * 256 + colG] = ((unsigned int)ua << 16) | ub;
        }
        const float ar = b2f(ua), br = b2f(ub);  // rounded, matches scanC replay
        Aa = ar * Aa; Bb = ar * Bb + br;
      }
      segA[mi] = Aa; segB[mi] = Bb;
    }
    // ordered combine across lhi (rows lhi*4..lhi*4+3 within each mi half)
    #pragma unroll
    for (int mi = 0; mi < 2; ++mi) {
      float A = segA[mi], Bv = segB[mi];
      {
        float Ap = __shfl_xor(A, 16), Bp = __shfl_xor(Bv, 16);
        float Bn = (lhi & 1) ? (A * Bp + Bv) : (Ap * Bv + Bp);
        A = A * Ap; Bv = Bn;
      }
      {
        float Ap = __shfl_xor(A, 32), Bp = __shfl_xor(Bv, 32);
        float Bn = (lhi & 2) ? (A * Bp + Bv) : (Ap * Bv + Bp);
        A = A * Ap; Bv = Bn;
      }
      segA[mi] = A; segB[mi] = Bv;
    }
    const float Ac = segA[1] * segA[0];
    const float Bc = segA[1] * segB[0] + segB[1];
    if (lhi == 0) { o[colG] = Ac; o[H_ + colG] = Bc; }
  }
}

// ---------------------------------------------------------------- scan C (mid): self-prefix + replay + residual
__global__ __launch_bounds__(256) void scanC_mid(const unsigned int* __restrict__ gh2,
                                                 const float* __restrict__ cAB,
                                                 bf16* __restrict__ h, int c0) {
  const int b = blockIdx.y;
  const int wv = threadIdx.x >> 6, lane = threadIdx.x & 63;
  const int c = c0 + blockIdx.x * 4 + wv;
  const int t4 = lane * 4;
  float4 hr = make_float4(0.5f, 0.5f, 0.5f, 0.5f);
  {
    const float* pk0 = cAB + (size_t)b * NC * 2 * H_ + t4;
    #pragma unroll 4
    for (int k = 0; k < c; ++k) {
      float4 a4 = *(const float4*)(pk0);
      float4 b4 = *(const float4*)(pk0 + H_);
      hr.x = a4.x*hr.x + b4.x; hr.y = a4.y*hr.y + b4.y;
      hr.z = a4.z*hr.z + b4.z; hr.w = a4.w*hr.w + b4.w;
      pk0 += 2 * H_;
    }
  }
  const unsigned int* p = gh2 + ((size_t)b * S_ + (size_t)c * L_) * 256 + t4;
  unsigned short* hp = (unsigned short*)(h + ((size_t)b * S_ + (size_t)c * L_) * H_);
  #pragma unroll 4
  for (int t = 0; t < L_; ++t) {
    uint4 pk = *(const uint4*)(p);
    ushort4 ru = *(const ushort4*)(hp + t4);
    hr.x = b2f(pk.x >> 16)*hr.x + b2f(pk.x & 0xffff);
    hr.y = b2f(pk.y >> 16)*hr.y + b2f(pk.y & 0xffff);
    hr.z = b2f(pk.z >> 16)*hr.z + b2f(pk.z & 0xffff);
    hr.w = b2f(pk.w >> 16)*hr.w + b2f(pk.w & 0xffff);
    ushort4 ov;
    ov.x = f2b(hr.x + b2f(ru.x));
    ov.y = f2b(hr.y + b2f(ru.y));
    ov.z = f2b(hr.z + b2f(ru.z));
    ov.w = f2b(hr.w + b2f(ru.w));
    *(ushort4*)(hp + t4) = ov;
    p += 256; hp += H_;
  }
}

// ---------------------------------------------------------------- output logits (last NM positions)
__global__ __launch_bounds__(256) void out_logits(const bf16* __restrict__ h,
                                                  const float* __restrict__ Wout,
                                                  const float* __restrict__ bout,
                                                  float* __restrict__ out) {
  const int r = blockIdx.x;            // b*NM + si
  const int b = r >> 4, si = r & 15;
  const int v = threadIdx.x;
  __shared__ float hs[H_];
  const size_t t = (size_t)b * S_ + (S_ - NM_ + si);
  hs[v] = b2f(((const unsigned short*)h)[t * H_ + v]);
  __syncthreads();
  float acc = bout[v];
  const float4* w4 = (const float4*)(Wout + (size_t)v * H_);
  #pragma unroll 8
  for (int k = 0; k < H_ / 4; ++k) {
    float4 wv = w4[k];
    float4 hv = *(const float4*)(hs + 4 * k);
    acc += wv.x * hv.x + wv.y * hv.y + wv.z * hv.z + wv.w * hv.w;
  }
  out[(size_t)r * V_ + v] = acc;
}

// ----------------------------------------------------------------
extern "C" void kernel_launch(void* const* d_in, const int* in_sizes, int n_in,
                              void* d_out, int out_size, void* d_ws, size_t ws_size,
                              hipStream_t stream) {
  const int*   x      = (const int*)d_in[0];
  const float* emb    = (const float*)d_in[1];
  const float* W0     = (const float*)d_in[2];
  const float* b0     = (const float*)d_in[3];
  const float* Wl     = (const float*)d_in[4];
  const float* bl     = (const float*)d_in[5];
  const float* Walign = (const float*)d_in[6];
  const float* Wout   = (const float*)d_in[7];
  const float* bout   = (const float*)d_in[8];
  (void)in_sizes; (void)n_in; (void)out_size; (void)ws_size;

  char* ws = (char*)d_ws;
  size_t off = 0;
  unsigned int* gh2 = (unsigned int*)(ws + off); off += (size_t)B_ * S_ * 256 * 4;  // 134 MB packed (a|bt)
  bf16*  h    = (bf16*)(ws + off);  off += (size_t)B_ * S_ * H_ * 2;     // 67 MB
  float* cAB  = (float*)(ws + off); off += (size_t)B_ * NC * 2 * H_ * 4; // 8 MB
  float* T0   = (float*)(ws + off); off += (size_t)V_ * 768 * 4;         // 768 KB
  bf16*  Wpk  = (bf16*)(ws + off);  off += (size_t)2 * GH * H_ * 2;      // 512 KB

  build_tables<<<256, 256, 0, stream>>>(emb, W0, b0, Walign, Wl, T0, Wpk);

  dim3 gscan(NC / 4, B_);
  // layer 0
  scanA_l0<<<gscan, 256, 0, stream>>>(x, T0, cAB);
  scanC_l0<<<gscan, 256, 0, stream>>>(x, T0, cAB, h);

  // layer 1 (full)
  gemm_scanA<<<B_ * NC, 256, 0, stream>>>(h, Wpk, bl, gh2, cAB, 0);
  scanC_mid<<<gscan, 256, 0, stream>>>(gh2, cAB, h, 0);

  // layer 2: only the last 4 chunks of gh/h are consumed downstream
  gemm_scanA<<<B_ * NC, 256, 0, stream>>>(h, Wpk + (size_t)GH * H_, bl + GH, gh2, cAB, NC - 4);
  scanC_mid<<<dim3(1, B_), 256, 0, stream>>>(gh2, cAB, h, NC - 4);

  out_logits<<<B_ * NM_, 256, 0, stream>>>(h, Wout, bout, (float*)d_out);
}